// Round 10
// baseline (2249.351 us; speedup 1.0000x reference)
//
#include <hip/hip_runtime.h>

constexpr int BB = 64, TT = 512, DD = 512, HH = 512;
constexpr int GG = 4 * HH;          // 2048 gate cols
constexpr int KK = DD + HH;         // 1024 fused K
constexpr int NBLK = 128, NTHR = 512;
// LDS: h[16 rows][512 bf16] swizzled (16KB) | zl[4][16][66] f32 | mask[16][16]
constexpr int LDS_H  = 16 * 1024;
constexpr int LDS_ZL = 4 * 16 * 66 * 4;
constexpr int LDS_BYTES = LDS_H + LDS_ZL + 16 * 16 * 4;

using short8 = __attribute__((ext_vector_type(8))) short;
using f32x4  = __attribute__((ext_vector_type(4))) float;

__device__ __host__ __forceinline__ unsigned short f2bf(float f) {
    union { float f; unsigned u; } v; v.f = f;
    unsigned u = v.u + 0x7fffu + ((v.u >> 16) & 1u);   // RNE
    return (unsigned short)(u >> 16);
}
__device__ __forceinline__ float fsig(float x) {
    return 1.f / (1.f + __expf(-x));
}
__device__ __forceinline__ float ftanh_(float x) {
    float e = __expf(2.f * fabsf(x));
    float r = 1.f - 2.f / (e + 1.f);
    return copysignf(r, x);
}

// ws: WB[2048][1024] bf16 (4MB) | hbuf[2][BB*HH/2] u32 pairs (128KB)
//     | flags[256] (A:0-127, B:128-255) | mpack[64][16]

__global__ void prep_kernel(const float* __restrict__ Wx,
                            const float* __restrict__ Wr,
                            const float* __restrict__ init_h,
                            const int*   __restrict__ mask,
                            unsigned short* __restrict__ WB,
                            unsigned* __restrict__ hbuf0,
                            unsigned* __restrict__ flags,
                            unsigned* __restrict__ mpack) {
    int idx = blockIdx.x * blockDim.x + threadIdx.x;
    if (idx < GG * KK) {                 // WB[g][k] = W[k][g], bf16
        int g = idx >> 10, k = idx & 1023;
        float v = (k < DD) ? Wx[(size_t)k * GG + g]
                           : Wr[(size_t)(k - DD) * GG + g];
        WB[idx] = f2bf(v);
    }
    if (idx < BB * HH / 2) {
        unsigned lo = f2bf(init_h[2 * idx]);
        unsigned hi = f2bf(init_h[2 * idx + 1]);
        hbuf0[idx] = lo | (hi << 16);
    }
    if (idx < 256) flags[idx] = 0u;
    if (idx < 64 * 16) {
        int b = idx >> 4, w = idx & 15;
        unsigned word = 0u;
        for (int tb = 0; tb < 32; ++tb)
            word |= (mask[b * TT + w * 32 + tb] != 0 ? 1u : 0u) << tb;
        mpack[idx] = word;
    }
}

// one (row, j) element per lane (lanes l<32 of the owning wave)
__device__ __forceinline__ void do_update(
    int t, int mrow, int row_g, int jl, int j_base,
    const float* zlp, const unsigned* m_lds, const float bias_r[4],
    float& c_reg, float& h_reg, float& po_reg,
    unsigned* nxt, float* __restrict__ out)
{
    float z[4];
    #pragma unroll
    for (int gt = 0; gt < 4; ++gt) {
        float s = bias_r[gt];
        #pragma unroll
        for (int p = 0; p < 4; ++p)
            s += zlp[(p * 16 + mrow) * 66 + gt * 16 + jl];
        z[gt] = s;
    }
    float ig = fsig(z[0]), fg = fsig(z[1]);
    float gg = ftanh_(z[2]), og = fsig(z[3]);
    float c_new = fg * c_reg + ig * gg;
    float h_new = og * ftanh_(c_new);
    bool msk = ((m_lds[mrow * 16 + (t >> 5)] >> (t & 31)) & 1u) != 0u;
    float ov = msk ? h_new : po_reg;
    float h2 = msk ? h_new : h_reg;
    c_reg = msk ? c_new : c_reg;
    h_reg = h2; po_reg = ov;
    out[((size_t)row_g * TT + t) * HH + j_base + jl] = ov;
    unsigned hb16 = f2bf(h2);
    unsigned other = (unsigned)__shfl_xor((int)hb16, 1);
    if ((jl & 1) == 0)
        __hip_atomic_store(nxt + (size_t)row_g * 256 + (j_base >> 1) + (jl >> 1),
                           hb16 | (other << 16), __ATOMIC_RELAXED,
                           __HIP_MEMORY_SCOPE_AGENT);
}

__global__ void __launch_bounds__(NTHR, 1)
lstm_kernel(const float* __restrict__ x,
            const unsigned short* __restrict__ WB,
            const float* __restrict__ bias,
            unsigned*    hbuf,
            unsigned*    flags,
            const unsigned* __restrict__ mpack,
            const float* __restrict__ init_h,
            const float* __restrict__ init_c,
            float* __restrict__ out)
{
    extern __shared__ char smem[];               // h rows [16][1024B] swizzled
    float*    zlp   = (float*)(smem + LDS_H);    // [4][16][66]
    unsigned* m_lds = (unsigned*)(smem + LDS_H + LDS_ZL);

    const int tid = threadIdx.x, bid = blockIdx.x;
    const int w = tid >> 6, l = tid & 63;
    const int kq  = w & 3;             // k-quarter (MFMA duty)
    const int nh  = w >> 2;            // n-half: gates {0,1} or {2,3}
    const int grp = w >> 2;            // update group: 0=A(rows0-7),1=B(8-15)
    const int q   = w & 3;             // updater sub-index
    const int qtr = bid >> 5, qb = bid & 31;
    const int qbase  = qtr * 16;
    const int j_base = qb * 16;

    // ---- persistent B-fragments (R6-verified layout) ----
    short8 bf[8][2];
    #pragma unroll
    for (int ni = 0; ni < 2; ++ni) {
        int col = (2 * nh + ni) * 16 + (l & 15);
        int g   = (col >> 4) * 512 + j_base + (col & 15);
        const unsigned short* wrow = WB + (size_t)g * KK + (l >> 4) * 8;
        #pragma unroll
        for (int i = 0; i < 4; ++i) {
            bf[i][ni]     = *(const short8*)(wrow + (kq * 4 + i) * 32);
            bf[4 + i][ni] = *(const short8*)(wrow + (16 + kq * 4 + i) * 32);
        }
    }

    // ---- per-lane update state (lanes l<32): elem = q*32 + l ----
    const int m_loc = q * 2 + (l >> 4);
    const int jl    = l & 15;
    const int mrow  = grp * 8 + m_loc;             // local row 0..15
    const int row_g = qbase + mrow;
    const int jg    = j_base + jl;
    float c_reg = 0.f, h_reg = 0.f, po_reg = 0.f;
    float bias_r[4] = {0.f, 0.f, 0.f, 0.f};
    if (l < 32) {
        c_reg = init_c[row_g * HH + jg];
        h_reg = init_h[row_g * HH + jg];
        #pragma unroll
        for (int gt = 0; gt < 4; ++gt) bias_r[gt] = bias[gt * 512 + jg];
    }
    for (int i = tid; i < 256; i += NTHR)
        m_lds[i] = mpack[(qbase + (i >> 4)) * 16 + (i & 15)];
    __syncthreads();

    const size_t OUT_HF = (size_t)BB * TT * HH;
    const size_t OUT_CF = OUT_HF + (size_t)BB * HH;

    for (int t = 0; t < TT; ++t) {
        const unsigned* curb = hbuf + (size_t)(t & 1) * (BB * HH / 2);
        unsigned*       nxtb = hbuf + (size_t)((t + 1) & 1) * (BB * HH / 2);

        uint4 ha0, ha1;
        if (grp == 0) {
            // pollA(t): flagA aged ~0.6 iter -> first-round hit
            const unsigned* fb = flags + qtr * 32;
            for (;;) {
                unsigned v = __hip_atomic_load(fb + (l & 31), __ATOMIC_RELAXED,
                                               __HIP_MEMORY_SCOPE_AGENT);
                if (__all(v >= (unsigned)t)) break;
                __builtin_amdgcn_s_sleep(1);
            }
            const unsigned* hp0 = curb + (size_t)(qbase + 2 * w) * 256 + l * 4;
            const unsigned* hp1 = curb + (size_t)(qbase + 2 * w + 1) * 256 + l * 4;
            asm volatile("global_load_dwordx4 %0, %2, off sc1\n\t"
                         "global_load_dwordx4 %1, %3, off sc1"
                         : "=&v"(ha0), "=&v"(ha1)
                         : "v"(hp0), "v"(hp1) : "memory");
        } else if (t > 0) {
            // deferred updateB(t-1): writes h[t] B-rows into curb
            if (l < 32)
                do_update(t - 1, mrow, row_g, jl, j_base, zlp, m_lds, bias_r,
                          c_reg, h_reg, po_reg, (unsigned*)curb, out);
        }

        // ---- x[t]: direct global->frag (A-layout: row=l&15, k=(l>>4)*8+e) ----
        f32x4 ax0 = {0.f, 0.f, 0.f, 0.f}, ax1 = {0.f, 0.f, 0.f, 0.f};
        {
            const float* xrow = x + ((size_t)(qbase + (l & 15)) * TT + t) * DD
                                  + (l >> 4) * 8;
            #pragma unroll
            for (int i = 0; i < 4; ++i) {
                const float4* xp = (const float4*)(xrow + (kq * 4 + i) * 32);
                float4 f0 = xp[0], f1 = xp[1];
                unsigned u0, u1, u2, u3;
                asm("v_cvt_pk_bf16_f32 %0, %1, %2" : "=v"(u0) : "v"(f0.x), "v"(f0.y));
                asm("v_cvt_pk_bf16_f32 %0, %1, %2" : "=v"(u1) : "v"(f0.z), "v"(f0.w));
                asm("v_cvt_pk_bf16_f32 %0, %1, %2" : "=v"(u2) : "v"(f1.x), "v"(f1.y));
                asm("v_cvt_pk_bf16_f32 %0, %1, %2" : "=v"(u3) : "v"(f1.z), "v"(f1.w));
                union { unsigned u[4]; short8 s; } cv;
                cv.u[0] = u0; cv.u[1] = u1; cv.u[2] = u2; cv.u[3] = u3;
                ax0 = __builtin_amdgcn_mfma_f32_16x16x32_bf16(cv.s, bf[i][0], ax0, 0, 0, 0);
                ax1 = __builtin_amdgcn_mfma_f32_16x16x32_bf16(cv.s, bf[i][1], ax1, 0, 0, 0);
            }
        }

        if (grp == 0) {   // stage hA rows 2w, 2w+1
            asm volatile("s_waitcnt vmcnt(0)" ::: "memory");
            __builtin_amdgcn_sched_barrier(0);
            union { uint4 u; short8 s; } c0, c1;
            c0.u = ha0; c1.u = ha1;
            int r0 = 2 * w, r1 = 2 * w + 1;
            *(short8*)(smem + r0 * 1024 + ((l * 16) ^ ((r0 & 7) << 4))) = c0.s;
            *(short8*)(smem + r1 * 1024 + ((l * 16) ^ ((r1 & 7) << 4))) = c1.s;
        }
        __syncthreads();   // bar1: ldsA ready; B(t-1) h-stores drained
        if (tid == 0 && t > 0)
            __hip_atomic_store(flags + 128 + qtr * 32 + qb, (unsigned)t,
                               __ATOMIC_RELAXED, __HIP_MEMORY_SCOPE_AGENT);

        // ---- phase A: h-MFMA (fresh rows 0-7) + zl rows 0-7 ----
        f32x4 a0 = ax0, a1 = ax1;
        #pragma unroll
        for (int i = 0; i < 4; ++i) {
            int ktL = kq * 4 + i;
            short8 av = *(const short8*)(smem + (l & 15) * 1024 +
                          ((ktL * 64 + (l >> 4) * 16) ^ ((l & 7) << 4)));
            a0 = __builtin_amdgcn_mfma_f32_16x16x32_bf16(av, bf[4 + i][0], a0, 0, 0, 0);
            a1 = __builtin_amdgcn_mfma_f32_16x16x32_bf16(av, bf[4 + i][1], a1, 0, 0, 0);
        }
        if ((l >> 4) < 2) {
            #pragma unroll
            for (int r = 0; r < 4; ++r) {
                int m = (l >> 4) * 4 + r;
                zlp[(kq * 16 + m) * 66 + (2 * nh) * 16 + (l & 15)]     = a0[r];
                zlp[(kq * 16 + m) * 66 + (2 * nh + 1) * 16 + (l & 15)] = a1[r];
            }
        }
        __syncthreads();   // bar2: zlA ready

        if (grp == 0) {
            if (l < 32)
                do_update(t, mrow, row_g, jl, j_base, zlp, m_lds, bias_r,
                          c_reg, h_reg, po_reg, nxtb, out);
        } else {
            // pollB(t) + stage hB rows 8+2(w-4), +1
            const unsigned* fb = flags + 128 + qtr * 32;
            for (;;) {
                unsigned v = __hip_atomic_load(fb + (l & 31), __ATOMIC_RELAXED,
                                               __HIP_MEMORY_SCOPE_AGENT);
                if (__all(v >= (unsigned)t)) break;
                __builtin_amdgcn_s_sleep(1);
            }
            int r0 = 8 + 2 * (w - 4), r1 = r0 + 1;
            const unsigned* hp0 = curb + (size_t)(qbase + r0) * 256 + l * 4;
            const unsigned* hp1 = curb + (size_t)(qbase + r1) * 256 + l * 4;
            uint4 hb0, hb1;
            asm volatile("global_load_dwordx4 %0, %2, off sc1\n\t"
                         "global_load_dwordx4 %1, %3, off sc1"
                         : "=&v"(hb0), "=&v"(hb1)
                         : "v"(hp0), "v"(hp1) : "memory");
            asm volatile("s_waitcnt vmcnt(0)" ::: "memory");
            __builtin_amdgcn_sched_barrier(0);
            union { uint4 u; short8 s; } c0, c1;
            c0.u = hb0; c1.u = hb1;
            *(short8*)(smem + r0 * 1024 + ((l * 16) ^ ((r0 & 7) << 4))) = c0.s;
            *(short8*)(smem + r1 * 1024 + ((l * 16) ^ ((r1 & 7) << 4))) = c1.s;
        }
        __syncthreads();   // bar3: ldsB ready; A h-stores drained
        if (tid == 0)
            __hip_atomic_store(flags + qtr * 32 + qb, (unsigned)(t + 1),
                               __ATOMIC_RELAXED, __HIP_MEMORY_SCOPE_AGENT);

        // ---- phase B: h-MFMA (fresh rows 8-15) + zl rows 8-15 ----
        f32x4 b0 = ax0, b1 = ax1;
        #pragma unroll
        for (int i = 0; i < 4; ++i) {
            int ktL = kq * 4 + i;
            short8 av = *(const short8*)(smem + (l & 15) * 1024 +
                          ((ktL * 64 + (l >> 4) * 16) ^ ((l & 7) << 4)));
            b0 = __builtin_amdgcn_mfma_f32_16x16x32_bf16(av, bf[4 + i][0], b0, 0, 0, 0);
            b1 = __builtin_amdgcn_mfma_f32_16x16x32_bf16(av, bf[4 + i][1], b1, 0, 0, 0);
        }
        if ((l >> 4) >= 2) {
            #pragma unroll
            for (int r = 0; r < 4; ++r) {
                int m = (l >> 4) * 4 + r;    // 8..15
                zlp[(kq * 16 + m) * 66 + (2 * nh) * 16 + (l & 15)]     = b0[r];
                zlp[(kq * 16 + m) * 66 + (2 * nh + 1) * 16 + (l & 15)] = b1[r];
            }
        }
        __syncthreads();   // bar4: zlB ready (updateB deferred to next iter)
    }

    // epilogue: deferred updateB(TT-1), then finals from registers
    if (grp == 1 && l < 32)
        do_update(TT - 1, mrow, row_g, jl, j_base, zlp, m_lds, bias_r,
                  c_reg, h_reg, po_reg, hbuf + (size_t)(TT & 1) * (BB * HH / 2), out);
    if (l < 32) {
        out[OUT_HF + (size_t)row_g * HH + jg] = h_reg;
        out[OUT_CF + (size_t)row_g * HH + jg] = c_reg;
    }
}

extern "C" void kernel_launch(void* const* d_in, const int* in_sizes, int n_in,
                              void* d_out, int out_size, void* d_ws, size_t ws_size,
                              hipStream_t stream) {
    const float* x      = (const float*)d_in[0];
    const float* init_h = (const float*)d_in[1];
    const float* init_c = (const float*)d_in[2];
    const float* Wx     = (const float*)d_in[3];
    const float* Wr     = (const float*)d_in[4];
    const float* bias   = (const float*)d_in[5];
    const int*   mask   = (const int*)d_in[6];
    float* out = (float*)d_out;

    unsigned short* WB    = (unsigned short*)d_ws;              // 4 MB
    unsigned*       hbuf  = (unsigned*)(WB + (size_t)GG * KK);  // 128 KB
    unsigned*       flags = hbuf + 2 * (BB * HH / 2);           // 1 KB
    unsigned*       mpack = flags + 256;                        // 4 KB

    prep_kernel<<<(GG * KK + 255) / 256, 256, 0, stream>>>(
        Wx, Wr, init_h, mask, WB, hbuf, flags, mpack);

    void* args[] = { (void*)&x, (void*)&WB, (void*)&bias, (void*)&hbuf,
                     (void*)&flags, (void*)&mpack, (void*)&init_h,
                     (void*)&init_c, (void*)&out };
    (void)hipLaunchCooperativeKernel((const void*)lstm_kernel, dim3(NBLK),
                                     dim3(NTHR), args, (unsigned)LDS_BYTES,
                                     stream);
}

// Round 11
// 2008.614 us; speedup vs baseline: 1.1199x; 1.1199x over previous
//
#include <hip/hip_runtime.h>

constexpr int BB = 64, TT = 512, DD = 512, HH = 512;
constexpr int GG = 4 * HH;          // 2048 gate cols
constexpr int KK = DD + HH;         // 1024 fused K
constexpr int NBLK = 128, NTHR = 512;
// LDS: x-A[16 rows][1024B] swizzled (16KB) | zl[64][65] f32 (16.6KB) | mask 1KB
constexpr int LDS_A  = 16 * 1024;
constexpr int LDS_ZL = 64 * 65 * 4;
constexpr int LDS_BYTES = LDS_A + LDS_ZL + 16 * 16 * 4;

using short8 = __attribute__((ext_vector_type(8))) short;
using f32x4  = __attribute__((ext_vector_type(4))) float;

__device__ __host__ __forceinline__ unsigned short f2bf(float f) {
    union { float f; unsigned u; } v; v.f = f;
    unsigned u = v.u + 0x7fffu + ((v.u >> 16) & 1u);   // RNE
    return (unsigned short)(u >> 16);
}
__device__ __forceinline__ float fsig(float x) {
    return 1.f / (1.f + __expf(-x));
}
__device__ __forceinline__ float ftanh_(float x) {
    float e = __expf(2.f * fabsf(x));
    float r = 1.f - 2.f / (e + 1.f);
    return copysignf(r, x);
}

// ws: WB[2048][1024] bf16 (4MB) | hbuf[2][BB*HH/2] u32 pairs (128KB)
//     | flags[128*16] line-padded (8KB) | mpack[64][16] (4KB)

__global__ void prep_kernel(const float* __restrict__ Wx,
                            const float* __restrict__ Wr,
                            const float* __restrict__ init_h,
                            const int*   __restrict__ mask,
                            unsigned short* __restrict__ WB,
                            unsigned* __restrict__ hbuf0,
                            unsigned* __restrict__ flags,
                            unsigned* __restrict__ mpack) {
    int idx = blockIdx.x * blockDim.x + threadIdx.x;
    if (idx < GG * KK) {                 // WB[g][k] = W[k][g], bf16
        int g = idx >> 10, k = idx & 1023;
        float v = (k < DD) ? Wx[(size_t)k * GG + g]
                           : Wr[(size_t)(k - DD) * GG + g];
        WB[idx] = f2bf(v);
    }
    if (idx < BB * HH / 2) {             // h0 as packed bf16 pairs
        unsigned lo = f2bf(init_h[2 * idx]);
        unsigned hi = f2bf(init_h[2 * idx + 1]);
        hbuf0[idx] = lo | (hi << 16);
    }
    if (idx < NBLK * 16) flags[idx] = 0u;
    if (idx < 64 * 16) {
        int b = idx >> 4, w = idx & 15;
        unsigned word = 0u;
        for (int tb = 0; tb < 32; ++tb)
            word |= (mask[b * TT + w * 32 + tb] != 0 ? 1u : 0u) << tb;
        mpack[idx] = word;
    }
}

__global__ void __launch_bounds__(NTHR, 1)
lstm_kernel(const float* __restrict__ x,
            const unsigned short* __restrict__ WB,
            const float* __restrict__ bias,
            unsigned*    hbuf,
            unsigned*    flags,                   // line-padded: idx*16
            const unsigned* __restrict__ mpack,
            const float* __restrict__ init_h,
            const float* __restrict__ init_c,
            float* __restrict__ out)
{
    extern __shared__ char smem[];               // x-A: [16 rows][1024B] swz
    float*    zlp   = (float*)(smem + LDS_A);    // [64][65]
    unsigned* m_lds = (unsigned*)(smem + LDS_A + LDS_ZL);  // [16][16]

    const int tid = threadIdx.x;
    const int bid = blockIdx.x;
    const int w   = tid >> 6;          // wave 0..7
    const int l   = tid & 63;
    const int kq  = w >> 1;            // k-quarter 0..3
    const int nh  = w & 1;             // n-half (n-tiles 2nh, 2nh+1)
    const int qtr = bid >> 5;          // batch quarter 0..3 (16 rows)
    const int qb  = bid & 31;          // j-slice in quarter
    const int qbase  = qtr * 16;
    const int j_base = qb * 16;

    // ---- persistent B-fragments: 8 ktiles x 2 n-tiles (64 VGPR) ----
    short8 bf[8][2];
    #pragma unroll
    for (int ni = 0; ni < 2; ++ni) {
        int col  = (2 * nh + ni) * 16 + (l & 15);
        int g    = (col >> 4) * 512 + j_base + (col & 15);
        const unsigned short* wrow = WB + (size_t)g * KK + (l >> 4) * 8;
        #pragma unroll
        for (int i = 0; i < 4; ++i) {
            bf[i][ni]     = *(const short8*)(wrow + (kq * 4 + i) * 32);
            bf[4 + i][ni] = *(const short8*)(wrow + (16 + kq * 4 + i) * 32);
        }
    }

    // ---- update mapping (tid < 256): one (row, j) each ----
    const int m_u = tid >> 4, jl = tid & 15;
    const int b_glob = qbase + m_u;
    const int jg = j_base + jl;
    float c_reg = 0.f, h_reg = 0.f, po_reg = 0.f;
    float bias_r[4];
    if (tid < 256) {
        c_reg = init_c[b_glob * HH + jg];
        h_reg = init_h[b_glob * HH + jg];
        #pragma unroll
        for (int gt = 0; gt < 4; ++gt) bias_r[gt] = bias[gt * 512 + jg];
    }
    for (int i = tid; i < 256; i += NTHR)
        m_lds[i] = mpack[(qbase + (i >> 4)) * 16 + (i & 15)];

    const size_t OUT_HF = (size_t)BB * TT * HH;
    const size_t OUT_CF = OUT_HF + (size_t)BB * HH;
    const int arow = l & 15;
    const int rsw  = (arow & 7) << 4;

    // ---- prologue: stage x[0] ----
    for (int u = tid; u < 1024; u += NTHR) {
        int row = u >> 6, c = u & 63;
        const float4* xp = (const float4*)(
            x + ((size_t)(qbase + row) * TT + 0) * DD + 8 * c);
        float4 f0 = xp[0], f1 = xp[1];
        short8 v;
        v[0] = (short)f2bf(f0.x); v[1] = (short)f2bf(f0.y);
        v[2] = (short)f2bf(f0.z); v[3] = (short)f2bf(f0.w);
        v[4] = (short)f2bf(f1.x); v[5] = (short)f2bf(f1.y);
        v[6] = (short)f2bf(f1.z); v[7] = (short)f2bf(f1.w);
        *(short8*)(smem + row * 1024 + ((16 * c) ^ ((row & 7) << 4))) = v;
    }
    __syncthreads();

    for (int t = 0; t < TT; ++t) {
        // ---- (1) poll own quarter's 32 line-padded flags ----
        {
            const unsigned tgt = (unsigned)t;
            const unsigned* fb = flags + qtr * 32 * 16;
            for (;;) {
                unsigned v = __hip_atomic_load(fb + (l & 31) * 16,
                                               __ATOMIC_RELAXED,
                                               __HIP_MEMORY_SCOPE_AGENT);
                if (__all(v >= tgt)) break;
                __builtin_amdgcn_s_sleep(1);
            }
        }

        // ---- (2) issue h A-fragment gathers (4x dwordx4 sc1 per lane) ----
        // lane l: row qbase+(l&15), bytes (kq*4+i)*64 + (l>>4)*16
        const char* hrp = (const char*)(hbuf + (size_t)(t & 1) * (BB * HH / 2))
                          + (size_t)(qbase + (l & 15)) * 1024
                          + (l >> 4) * 16 + (size_t)kq * 256;
        uint4 hg0, hg1, hg2, hg3;
        asm volatile("global_load_dwordx4 %0, %4, off sc1\n\t"
                     "global_load_dwordx4 %1, %5, off sc1\n\t"
                     "global_load_dwordx4 %2, %6, off sc1\n\t"
                     "global_load_dwordx4 %3, %7, off sc1"
                     : "=&v"(hg0), "=&v"(hg1), "=&v"(hg2), "=&v"(hg3)
                     : "v"(hrp), "v"(hrp + 64), "v"(hrp + 128), "v"(hrp + 192)
                     : "memory");

        // ---- (3) x-MFMAs (LDS, staged in prev tail) hide gather latency ----
        f32x4 acc0 = {0.f, 0.f, 0.f, 0.f}, acc1 = {0.f, 0.f, 0.f, 0.f};
        #pragma unroll
        for (int i = 0; i < 4; ++i) {
            int kt = kq * 4 + i;
            short8 a = *(const short8*)(
                smem + arow * 1024 + ((kt * 64 + (l >> 4) * 16) ^ rsw));
            acc0 = __builtin_amdgcn_mfma_f32_16x16x32_bf16(a, bf[i][0], acc0, 0, 0, 0);
            acc1 = __builtin_amdgcn_mfma_f32_16x16x32_bf16(a, bf[i][1], acc1, 0, 0, 0);
        }

        // ---- (4) wait gathers, h-MFMAs straight from registers ----
        asm volatile("s_waitcnt vmcnt(0)" ::: "memory");
        __builtin_amdgcn_sched_barrier(0);
        {
            union { uint4 u; short8 s; } c0, c1, c2, c3;
            c0.u = hg0; c1.u = hg1; c2.u = hg2; c3.u = hg3;
            acc0 = __builtin_amdgcn_mfma_f32_16x16x32_bf16(c0.s, bf[4][0], acc0, 0, 0, 0);
            acc1 = __builtin_amdgcn_mfma_f32_16x16x32_bf16(c0.s, bf[4][1], acc1, 0, 0, 0);
            acc0 = __builtin_amdgcn_mfma_f32_16x16x32_bf16(c1.s, bf[5][0], acc0, 0, 0, 0);
            acc1 = __builtin_amdgcn_mfma_f32_16x16x32_bf16(c1.s, bf[5][1], acc1, 0, 0, 0);
            acc0 = __builtin_amdgcn_mfma_f32_16x16x32_bf16(c2.s, bf[6][0], acc0, 0, 0, 0);
            acc1 = __builtin_amdgcn_mfma_f32_16x16x32_bf16(c2.s, bf[6][1], acc1, 0, 0, 0);
            acc0 = __builtin_amdgcn_mfma_f32_16x16x32_bf16(c3.s, bf[7][0], acc0, 0, 0, 0);
            acc1 = __builtin_amdgcn_mfma_f32_16x16x32_bf16(c3.s, bf[7][1], acc1, 0, 0, 0);
        }

        // ---- (5) zl write (65-stride pad) ----
        #pragma unroll
        for (int r = 0; r < 4; ++r) {
            int zrow = kq * 16 + (l >> 4) * 4 + r;
            zlp[zrow * 65 + (2 * nh) * 16 + (l & 15)]     = acc0[r];
            zlp[zrow * 65 + (2 * nh + 1) * 16 + (l & 15)] = acc1[r];
        }
        __syncthreads();   // bar1: zl ready

        // ---- (6) update (waves 0-3) || stage x[t+1] (waves 4-7) ----
        unsigned* nxtb = hbuf + (size_t)((t + 1) & 1) * (BB * HH / 2);
        if (tid < 256) {
            bool msk = ((m_lds[m_u * 16 + (t >> 5)] >> (t & 31)) & 1u) != 0u;
            float z[4];
            #pragma unroll
            for (int gt = 0; gt < 4; ++gt) {
                float s = bias_r[gt];
                #pragma unroll
                for (int p = 0; p < 4; ++p)
                    s += zlp[(p * 16 + m_u) * 65 + gt * 16 + jl];
                z[gt] = s;
            }
            float ig = fsig(z[0]);
            float fg = fsig(z[1]);
            float gg = ftanh_(z[2]);
            float og = fsig(z[3]);
            float c_new = fg * c_reg + ig * gg;
            float h_new = og * ftanh_(c_new);
            float ov = msk ? h_new : po_reg;
            float h2 = msk ? h_new : h_reg;
            float c2 = msk ? c_new : c_reg;
            out[((size_t)b_glob * TT + t) * HH + jg] = ov;
            unsigned hb16 = f2bf(h2);
            unsigned other = (unsigned)__shfl_xor((int)hb16, 1);
            if ((jl & 1) == 0)
                __hip_atomic_store(nxtb + (size_t)b_glob * 256 + ((j_base + jl) >> 1),
                                   hb16 | (other << 16), __ATOMIC_RELAXED,
                                   __HIP_MEMORY_SCOPE_AGENT);
            c_reg = c2; h_reg = h2; po_reg = ov;
        } else if (t + 1 < TT) {
            for (int u = tid - 256; u < 1024; u += 256) {
                int row = u >> 6, c = u & 63;
                const float4* xp = (const float4*)(
                    x + ((size_t)(qbase + row) * TT + (t + 1)) * DD + 8 * c);
                float4 f0 = xp[0], f1 = xp[1];
                short8 v;
                v[0] = (short)f2bf(f0.x); v[1] = (short)f2bf(f0.y);
                v[2] = (short)f2bf(f0.z); v[3] = (short)f2bf(f0.w);
                v[4] = (short)f2bf(f1.x); v[5] = (short)f2bf(f1.y);
                v[6] = (short)f2bf(f1.z); v[7] = (short)f2bf(f1.w);
                *(short8*)(smem + row * 1024 + ((16 * c) ^ ((row & 7) << 4))) = v;
            }
        }
        // bar2: per-wave vmcnt drain -> all h sc1-stores at coherence point
        // before the flag store; also protects next iter's x-A LDS reads.
        __syncthreads();

        if (tid == 0)
            __hip_atomic_store(flags + (qtr * 32 + qb) * 16, (unsigned)(t + 1),
                               __ATOMIC_RELAXED, __HIP_MEMORY_SCOPE_AGENT);
    }

    if (tid < 256) {
        out[OUT_HF + (size_t)b_glob * HH + jg] = h_reg;
        out[OUT_CF + (size_t)b_glob * HH + jg] = c_reg;
    }
}

extern "C" void kernel_launch(void* const* d_in, const int* in_sizes, int n_in,
                              void* d_out, int out_size, void* d_ws, size_t ws_size,
                              hipStream_t stream) {
    const float* x      = (const float*)d_in[0];
    const float* init_h = (const float*)d_in[1];
    const float* init_c = (const float*)d_in[2];
    const float* Wx     = (const float*)d_in[3];
    const float* Wr     = (const float*)d_in[4];
    const float* bias   = (const float*)d_in[5];
    const int*   mask   = (const int*)d_in[6];
    float* out = (float*)d_out;

    unsigned short* WB    = (unsigned short*)d_ws;              // 4 MB
    unsigned*       hbuf  = (unsigned*)(WB + (size_t)GG * KK);  // 128 KB
    unsigned*       flags = hbuf + 2 * (BB * HH / 2);           // 8 KB padded
    unsigned*       mpack = flags + NBLK * 16;                  // 4 KB

    prep_kernel<<<(GG * KK + 255) / 256, 256, 0, stream>>>(
        Wx, Wr, init_h, mask, WB, hbuf, flags, mpack);

    void* args[] = { (void*)&x, (void*)&WB, (void*)&bias, (void*)&hbuf,
                     (void*)&flags, (void*)&mpack, (void*)&init_h,
                     (void*)&init_c, (void*)&out };
    (void)hipLaunchCooperativeKernel((const void*)lstm_kernel, dim3(NBLK),
                                     dim3(NTHR), args, (unsigned)LDS_BYTES,
                                     stream);
}

// Round 13
// 1388.309 us; speedup vs baseline: 1.6202x; 1.4468x over previous
//
#include <hip/hip_runtime.h>

constexpr int BB = 64, TT = 512, DD = 512, HH = 512;
constexpr int GG = 4 * HH;          // 2048 gate cols
constexpr int KK = DD + HH;         // 1024 fused K
constexpr int NBLK = 128, NTHR = 512;
// LDS: xA[8][1024B] | hA[8][1024B] | zl[4][16][129] f32 | mask[8][16]
constexpr int LDS_ZL = 4 * 16 * 129 * 4;
constexpr int LDS_BYTES = 8192 + 8192 + LDS_ZL + 512;

using short8 = __attribute__((ext_vector_type(8))) short;
using f32x4  = __attribute__((ext_vector_type(4))) float;

__device__ __host__ __forceinline__ unsigned short f2bf(float f) {
    union { float f; unsigned u; } v; v.f = f;
    unsigned u = v.u + 0x7fffu + ((v.u >> 16) & 1u);   // RNE
    return (unsigned short)(u >> 16);
}
__device__ __forceinline__ float fsig(float x) {
    return 1.f / (1.f + __expf(-x));
}
__device__ __forceinline__ float ftanh_(float x) {
    float e = __expf(2.f * fabsf(x));
    float r = 1.f - 2.f / (e + 1.f);
    return copysignf(r, x);
}

// ws: WB[2048][1024] bf16 (4MB) | hbuf[8 grp][2][8][256] u32 (128KB)
//     | flags[8 grp][16][16pad] (8KB) | mpack[64][16] (4KB)

__global__ void prep_kernel(const float* __restrict__ Wx,
                            const float* __restrict__ Wr,
                            const float* __restrict__ init_h,
                            const int*   __restrict__ mask,
                            unsigned short* __restrict__ WB,
                            unsigned* __restrict__ hbuf0,
                            unsigned* __restrict__ flags,
                            unsigned* __restrict__ mpack) {
    int idx = blockIdx.x * blockDim.x + threadIdx.x;
    if (idx < GG * KK) {                 // WB[g][k] = W[k][g], bf16
        int g = idx >> 10, k = idx & 1023;
        float v = (k < DD) ? Wx[(size_t)k * GG + g]
                           : Wr[(size_t)(k - DD) * GG + g];
        WB[idx] = f2bf(v);
    }
    if (idx < BB * HH / 2) {             // h0 pairs into [grp][buf0][row][256]
        int b = idx >> 8, p = idx & 255;
        unsigned lo = f2bf(init_h[b * HH + 2 * p]);
        unsigned hi = f2bf(init_h[b * HH + 2 * p + 1]);
        hbuf0[(b >> 3) * 4096 + (b & 7) * 256 + p] = lo | (hi << 16);
    }
    if (idx < 2048) flags[idx] = 0u;
    if (idx < 64 * 16) {
        int b = idx >> 4, w = idx & 15;
        unsigned word = 0u;
        for (int tb = 0; tb < 32; ++tb)
            word |= (mask[b * TT + w * 32 + tb] != 0 ? 1u : 0u) << tb;
        mpack[idx] = word;
    }
}

__global__ void __launch_bounds__(NTHR, 1)
lstm_kernel(const float* __restrict__ x,
            const unsigned short* __restrict__ WB,
            const float* __restrict__ bias,
            unsigned*    hbuf,                    // sc1-only traffic
            unsigned*    flags,                   // sc1-only, line-padded
            const unsigned* __restrict__ mpack,
            const float* __restrict__ init_h,
            const float* __restrict__ init_c,
            float* __restrict__ out)
{
    extern __shared__ char smem[];
    char*     smx   = smem;                       // x A-tile [8][1024B] swz
    char*     smh   = smem + 8192;                // h A-tile [8][1024B] swz
    float*    zlp   = (float*)(smem + 16384);     // [4][16][129]
    unsigned* m_lds = (unsigned*)(smem + 16384 + LDS_ZL);  // [8][16]

    const int tid = threadIdx.x;
    const int bid = blockIdx.x;
    const int w   = tid >> 6;          // wave 0..7
    const int l   = tid & 63;
    const int kq  = w >> 1;            // k-quarter 0..3
    const int nh  = w & 1;             // n-half: n-tiles 4nh..4nh+3

    // static groups: grp = bid&7 (round-robin -> co-XCD tendency, not relied on)
    const int grp    = bid & 7;        // batch octet: rows grp*8..+7
    const int qb     = bid >> 3;       // j-slice 0..15
    const int j_base = qb * 32;
    const int obase  = grp * 8;

    // ---- persistent B-fragments: 8 ktiles x 4 n-tiles (128 VGPR) ----
    short8 bf[8][4];
    #pragma unroll
    for (int nt = 0; nt < 4; ++nt) {
        int n   = nh * 4 + nt;
        int col = n * 16 + (l & 15);                   // 0..127
        int g   = (col >> 5) * 512 + j_base + (col & 31);
        const unsigned short* wrow = WB + (size_t)g * KK + (l >> 4) * 8;
        #pragma unroll
        for (int i = 0; i < 4; ++i) {
            bf[i][nt]     = *(const short8*)(wrow + (kq * 4 + i) * 32);
            bf[4 + i][nt] = *(const short8*)(wrow + (16 + kq * 4 + i) * 32);
        }
    }

    // ---- update mapping (tid < 256): one (row, j) each ----
    const int m_u = tid >> 5, jl = tid & 31;           // m_u 0..7, jl 0..31
    const int b_glob = obase + m_u;
    const int jg = j_base + jl;
    float c_reg = 0.f, h_reg = 0.f, po_reg = 0.f;
    float bias_r[4] = {0.f, 0.f, 0.f, 0.f};
    if (tid < 256) {
        c_reg = init_c[b_glob * HH + jg];
        h_reg = init_h[b_glob * HH + jg];
        #pragma unroll
        for (int gt = 0; gt < 4; ++gt) bias_r[gt] = bias[gt * 512 + jg];
    }
    for (int i = tid; i < 128; i += NTHR)
        m_lds[i] = mpack[(obase + (i >> 4)) * 16 + (i & 15)];

    unsigned* hgrp = hbuf + grp * 4096;                // [2][8][256]
    const size_t OUT_HF = (size_t)BB * TT * HH;
    const size_t OUT_CF = OUT_HF + (size_t)BB * HH;
    const int arow = l & 7;            // A row (lanes 8-15 duplicate rows 0-7)
    const int rsw  = arow << 4;

    // ---- prologue: stage x[0] ----
    for (int u = tid; u < 512; u += NTHR) {
        int row = u >> 6, c = u & 63;
        const float4* xp = (const float4*)(
            x + ((size_t)(obase + row) * TT + 0) * DD + 8 * c);
        float4 f0 = xp[0], f1 = xp[1];
        short8 v;
        v[0] = (short)f2bf(f0.x); v[1] = (short)f2bf(f0.y);
        v[2] = (short)f2bf(f0.z); v[3] = (short)f2bf(f0.w);
        v[4] = (short)f2bf(f1.x); v[5] = (short)f2bf(f1.y);
        v[6] = (short)f2bf(f1.z); v[7] = (short)f2bf(f1.w);
        *(short8*)(smx + row * 1024 + ((16 * c) ^ ((row & 7) << 4))) = v;
    }
    __syncthreads();

    for (int t = 0; t < TT; ++t) {
        // ---- (1) poll own group's 16 line-padded flags (all waves) ----
        {
            const unsigned tgt = (unsigned)t;
            const unsigned* fb = flags + grp * 256 + (l & 15) * 16;
            for (;;) {
                unsigned v = __hip_atomic_load(fb, __ATOMIC_RELAXED,
                                               __HIP_MEMORY_SCOPE_AGENT);
                if (__all(v >= tgt)) break;
                __builtin_amdgcn_s_sleep(1);
            }
        }

        // ---- (2) issue h row load: wave w -> row w (1KB, coalesced sc1) ----
        const unsigned* curb = hgrp + (size_t)(t & 1) * 2048;
        unsigned*       nxtb = hgrp + (size_t)((t + 1) & 1) * 2048;
        uint4 hv;
        {
            const unsigned* hp = curb + w * 256 + l * 4;
            asm volatile("global_load_dwordx4 %0, %1, off sc1"
                         : "=v"(hv) : "v"(hp) : "memory");
        }

        // ---- (3) x-MFMAs (LDS staged in prev tail) hide h-load latency ----
        f32x4 acc[4] = {{0,0,0,0},{0,0,0,0},{0,0,0,0},{0,0,0,0}};
        #pragma unroll
        for (int i = 0; i < 4; ++i) {
            int kt = kq * 4 + i;
            short8 a = *(const short8*)(
                smx + arow * 1024 + ((kt * 64 + (l >> 4) * 16) ^ rsw));
            #pragma unroll
            for (int nt = 0; nt < 4; ++nt)
                acc[nt] = __builtin_amdgcn_mfma_f32_16x16x32_bf16(a, bf[i][nt], acc[nt], 0, 0, 0);
        }

        // ---- (4) wait h, stage into LDS ----
        asm volatile("s_waitcnt vmcnt(0)" ::: "memory");
        __builtin_amdgcn_sched_barrier(0);
        {
            union { uint4 u; short8 s; } cv; cv.u = hv;
            *(short8*)(smh + w * 1024 + ((l * 16) ^ ((w & 7) << 4))) = cv.s;
        }
        __syncthreads();   // bar A: smh ready

        // ---- (5) h-MFMAs + zl write (live rows 0-7 only) ----
        #pragma unroll
        for (int i = 0; i < 4; ++i) {
            int kt = kq * 4 + i;
            short8 a = *(const short8*)(
                smh + arow * 1024 + ((kt * 64 + (l >> 4) * 16) ^ rsw));
            #pragma unroll
            for (int nt = 0; nt < 4; ++nt)
                acc[nt] = __builtin_amdgcn_mfma_f32_16x16x32_bf16(a, bf[4 + i][nt], acc[nt], 0, 0, 0);
        }
        if ((l >> 4) < 2) {
            #pragma unroll
            for (int nt = 0; nt < 4; ++nt) {
                int n = nh * 4 + nt;
                #pragma unroll
                for (int r = 0; r < 4; ++r) {
                    int m = (l >> 4) * 4 + r;      // 0..7
                    zlp[(kq * 16 + m) * 129 + n * 16 + (l & 15)] = acc[nt][r];
                }
            }
        }
        __syncthreads();   // bar B: zl ready

        // ---- (6) update (waves 0-3) || stage x[t+1] (waves 4-7) ----
        if (tid < 256) {
            bool msk = ((m_lds[m_u * 16 + (t >> 5)] >> (t & 31)) & 1u) != 0u;
            float z[4];
            #pragma unroll
            for (int gt = 0; gt < 4; ++gt) {
                float s = bias_r[gt];
                #pragma unroll
                for (int p = 0; p < 4; ++p)
                    s += zlp[(p * 16 + m_u) * 129 + gt * 32 + jl];
                z[gt] = s;
            }
            float ig = fsig(z[0]);
            float fg = fsig(z[1]);
            float gg = ftanh_(z[2]);
            float og = fsig(z[3]);
            float c_new = fg * c_reg + ig * gg;
            float h_new = og * ftanh_(c_new);
            float ov = msk ? h_new : po_reg;
            float h2 = msk ? h_new : h_reg;
            float c2 = msk ? c_new : c_reg;
            out[((size_t)b_glob * TT + t) * HH + jg] = ov;
            unsigned hb16 = f2bf(h2);
            unsigned other = (unsigned)__shfl_xor((int)hb16, 1);
            if ((jl & 1) == 0)
                __hip_atomic_store(nxtb + m_u * 256 + qb * 16 + (jl >> 1),
                                   hb16 | (other << 16), __ATOMIC_RELAXED,
                                   __HIP_MEMORY_SCOPE_AGENT);
            c_reg = c2; h_reg = h2; po_reg = ov;
        } else if (t + 1 < TT) {
            for (int u = tid - 256; u < 512; u += 256) {
                int row = u >> 6, c = u & 63;
                const float4* xp = (const float4*)(
                    x + ((size_t)(obase + row) * TT + (t + 1)) * DD + 8 * c);
                float4 f0 = xp[0], f1 = xp[1];
                short8 v;
                v[0] = (short)f2bf(f0.x); v[1] = (short)f2bf(f0.y);
                v[2] = (short)f2bf(f0.z); v[3] = (short)f2bf(f0.w);
                v[4] = (short)f2bf(f1.x); v[5] = (short)f2bf(f1.y);
                v[6] = (short)f2bf(f1.z); v[7] = (short)f2bf(f1.w);
                *(short8*)(smx + row * 1024 + ((16 * c) ^ ((row & 7) << 4))) = v;
            }
        }
        // bar C: per-wave vmcnt drain -> h sc1-stores at coherence point
        // before the flag store; also: smx staged, zl consumed.
        __syncthreads();

        if (tid == 0)
            __hip_atomic_store(flags + (grp * 16 + qb) * 16, (unsigned)(t + 1),
                               __ATOMIC_RELAXED, __HIP_MEMORY_SCOPE_AGENT);
    }

    if (tid < 256) {
        out[OUT_HF + (size_t)b_glob * HH + jg] = h_reg;
        out[OUT_CF + (size_t)b_glob * HH + jg] = c_reg;
    }
}

extern "C" void kernel_launch(void* const* d_in, const int* in_sizes, int n_in,
                              void* d_out, int out_size, void* d_ws, size_t ws_size,
                              hipStream_t stream) {
    const float* x      = (const float*)d_in[0];
    const float* init_h = (const float*)d_in[1];
    const float* init_c = (const float*)d_in[2];
    const float* Wx     = (const float*)d_in[3];
    const float* Wr     = (const float*)d_in[4];
    const float* bias   = (const float*)d_in[5];
    const int*   mask   = (const int*)d_in[6];
    float* out = (float*)d_out;

    unsigned short* WB    = (unsigned short*)d_ws;              // 4 MB
    unsigned*       hbuf  = (unsigned*)(WB + (size_t)GG * KK);  // 128 KB
    unsigned*       flags = hbuf + 8 * 4096;                    // 8 KB
    unsigned*       mpack = flags + 2048;                       // 4 KB

    prep_kernel<<<(GG * KK + 255) / 256, 256, 0, stream>>>(
        Wx, Wr, init_h, mask, WB, hbuf, flags, mpack);

    void* args[] = { (void*)&x, (void*)&WB, (void*)&bias, (void*)&hbuf,
                     (void*)&flags, (void*)&mpack, (void*)&init_h,
                     (void*)&init_c, (void*)&out };
    (void)hipLaunchCooperativeKernel((const void*)lstm_kernel, dim3(NBLK),
                                     dim3(NTHR), args, (unsigned)LDS_BYTES,
                                     stream);
}